// Round 8
// baseline (183.110 us; speedup 1.0000x reference)
//
#include <hip/hip_runtime.h>
#include <math.h>

// Problem: SphericalHarmonicTransform, L=8, RCUT=5, N=4194304 points.
// out[81] = sum over points of (modified) solid harmonic terms.
// R8: 2-POINT SIMD packing (ptA in .x, ptB in .y of every f32x2). Unlike R7's
//     real/imag packing, points are fully independent -> zero lane-crossing,
//     zero vector-build overhead; the whole scalar body maps 1:1 to v_pk_* at
//     half the per-point instruction count (~260/pt static). Accumulators stay
//     SCALAR (81 regs) to hold VGPR ~240 < 256; launch_bounds(256,1) frees the
//     allocator. Residency ~2 waves/SIMD is fine: occupancy was proven
//     non-binding (R1 2blk/CU == R3 4blk/CU, identical time & busy%).
// Known facts: ~60us bench-vs-kernel gap = fixed harness overhead (R5 fused
//     test). (256,4) clamps VGPR->64 and spills 1.1GB (R2). Transposed-ws
//     WRITE_SIZE ~2.6MB is write-allocate padding, not spill (R4/R5) — but a
//     JUMP above that indicates real spill.

typedef float f32x2 __attribute__((ext_vector_type(2)));

#define NL 8               // L
#define NACC 45            // (l,m) pairs, m<=l, l<=8
#define NBLK 1024
#define NTHR 256

__device__ __forceinline__ f32x2 sp(float v) { return f32x2{v, v}; }

__device__ __forceinline__ float waveReduce(float v) {
    v += __shfl_down(v, 32);
    v += __shfl_down(v, 16);
    v += __shfl_down(v, 8);
    v += __shfl_down(v, 4);
    v += __shfl_down(v, 2);
    v += __shfl_down(v, 1);
    return v;
}

// Two points per call; every f32x2 is (pointA, pointB).
__device__ __forceinline__ void pair_body(
    float xA, float yA, float zA,
    float xB, float yB, float zB,
    float* __restrict__ accr, float* __restrict__ acci)
{
    const float FACT[9] = {1.f, 1.f, 2.f, 6.f, 24.f, 120.f, 720.f, 5040.f, 40320.f};

    // --- per-point scalar preamble (transcendentals have no packed form) ---
    float x0s[2], invsc[2];
#pragma unroll
    for (int k = 0; k < 2; ++k) {
        const float x = k ? xB : xA;
        const float y = k ? yB : yA;
        const float z = k ? zB : zA;
        const float r2 = x * x + y * y + z * z;
        const bool valid = r2 > 0.0f;
        const float inv0 = __builtin_amdgcn_rsqf(r2);   // 1/sqrt(r2)
        const float norm = r2 * inv0;                   // NaN at r2=0, masked below
        float cut = 0.5f * (__cosf(norm * 0.6283185307179586f) + 1.0f);
        cut = (r2 > 25.0f) ? 0.0f : cut;
        cut = valid ? cut : 0.0f;                       // kills NaN at r2=0
        invsc[k] = valid ? inv0 : 1.0f;
        x0s[k] = z * cut;
    }

    // h_l = x0c * inv^l  (cutoff + 1/r^l deferred out of the sums)
    const f32x2 invp = { invsc[0], invsc[1] };
    f32x2 h[9];
    h[0] = f32x2{ x0s[0], x0s[1] };
#pragma unroll
    for (int l = 1; l <= NL; ++l) h[l] = h[l - 1] * invp;

    const f32x2 w1 = { -0.5f * xA, -0.5f * xB };   // xpr
    const f32x2 wi = { -0.5f * yA, -0.5f * yB };   // xpi == xmi
    const f32x2 w2 = {  0.5f * xA,  0.5f * xB };   // xmr

    // powcmplx replication (per packed pair of points):
    //  n=0 -> (1,0); n=1 -> w; n=2 -> special (r^2-i^2, 2ri);
    //  n>=3 -> buggy chain: nr = wr*br - wi*bi; ni = wr*bi + wi*nr (uses NEW nr)
    //  chain's k=2 real == special real; its (buggy) imag feeds k>=3.
    f32x2 a[9], b[9], c[9], d[9];   // a=z1r b=z1i c=z2r d=z2i
    a[0] = sp(1.f); b[0] = sp(0.f); c[0] = sp(1.f); d[0] = sp(0.f);
    a[1] = w1;      b[1] = wi;      c[1] = w2;      d[1] = wi;
    a[2] = w1 * w1 - wi * wi;  b[2] = (w1 + w1) * wi;
    c[2] = w2 * w2 - wi * wi;  d[2] = (w2 + w2) * wi;
    {
        f32x2 cr = a[2];
        f32x2 ci = w1 * wi + wi * cr;              // buggy chain imag at k=2
#pragma unroll
        for (int k = 3; k <= NL; ++k) {
            const f32x2 nr = w1 * cr - wi * ci;
            const f32x2 ni = w1 * ci + wi * nr;    // buggy: uses nr
            cr = nr; ci = ni;
            a[k] = nr; b[k] = ni;
        }
    }
    {
        f32x2 cr = c[2];
        f32x2 ci = w2 * wi + wi * cr;              // buggy chain imag at k=2
#pragma unroll
        for (int k = 3; k <= NL; ++k) {
            const f32x2 nr = w2 * cr - wi * ci;
            const f32x2 ni = w2 * ci + wi * nr;    // buggy: uses nr
            cr = nr; ci = ni;
            c[k] = nr; d[k] = ni;
        }
    }

    f32x2 sqa[9];
#pragma unroll
    for (int p = 0; p <= NL; ++p) sqa[p] = a[p] * a[p];

    // m-outer: Y_m(p) = (a_p^2 - d_q^2, a_p d_q + b_p c_q)/(p! q!), q=p-m;
    // sr/si(l,m) = sum_p Y * (1/s!), s=l-2p+m (9 distinct hoistable consts);
    // scalar acc(l,m) += sr.x*h.x + sr.y*h.y  (2 fmac, keeps acc at 81 regs).
#pragma unroll
    for (int m = 0; m <= NL; ++m) {
        f32x2 Yr[9], Yi[9];
#pragma unroll
        for (int p = 0; p <= NL; ++p) {
            if (p >= m && 2 * p - m <= NL) {
                const int q = p - m;
                const float cpq = 1.0f / (FACT[p] * FACT[q]);   // compile-time
                Yr[p] = (sqa[p] - d[q] * d[q]) * sp(cpq);
                if (m > 0)
                    Yi[p] = (a[p] * d[q] + b[p] * c[q]) * sp(cpq);
            }
        }
#pragma unroll
        for (int l = m; l <= NL; ++l) {
            f32x2 sr = sp(0.f), si = sp(0.f);
#pragma unroll
            for (int p = 0; p <= NL; ++p) {
                if (p >= m && 2 * p - m <= l) {
                    const int sidx = l - 2 * p + m;
                    const float is = 1.0f / FACT[sidx];         // 9 uniques
                    sr += Yr[p] * sp(is);
                    if (m > 0) si += Yi[p] * sp(is);
                }
            }
            const int ai = l * (l + 1) / 2 + m;
            accr[ai] = fmaf(sr.y, h[l].y, fmaf(sr.x, h[l].x, accr[ai]));
            if (m > 0)
                acci[ai] = fmaf(si.y, h[l].y, fmaf(si.x, h[l].x, acci[ai]));
        }
    }
}

__global__ __launch_bounds__(256, 1)   // allocator free up to 512 VGPR
void sht_main(const float* __restrict__ pos, float* __restrict__ ws, int n) {
    float accr[NACC], acci[NACC];
#pragma unroll
    for (int i = 0; i < NACC; ++i) { accr[i] = 0.f; acci[i] = 0.f; }

    const int t = blockIdx.x * NTHR + threadIdx.x;
    const int nthreads = NBLK * NTHR;                       // 262144
    const int nchunks = (n / 4 + nthreads - 1) / nthreads;  // 4 for N=2^22

    for (int c = 0; c < nchunks; ++c) {
        const int idx = (c * nthreads + t) * 4;             // 4 contiguous points
        float xs[4], ys[4], zs[4];
        if (idx + 4 <= n) {
            // 3x float4 = 48B, 16B-aligned (idx%4==0 -> offset multiple of 48B)
            const float4* p4 = reinterpret_cast<const float4*>(pos + (size_t)3 * idx);
            const float4 q0 = p4[0];    // x0 y0 z0 x1
            const float4 q1 = p4[1];    // y1 z1 x2 y2
            const float4 q2 = p4[2];    // z2 x3 y3 z3
            xs[0] = q0.x; ys[0] = q0.y; zs[0] = q0.z;
            xs[1] = q0.w; ys[1] = q1.x; zs[1] = q1.y;
            xs[2] = q1.z; ys[2] = q1.w; zs[2] = q2.x;
            xs[3] = q2.y; ys[3] = q2.z; zs[3] = q2.w;
        } else {
#pragma unroll
            for (int k = 0; k < 4; ++k) {
                const int i = idx + k;
                const bool ok = i < n;
                xs[k] = ok ? pos[3 * i + 0] : 0.f;          // zero-pad: contributes 0
                ys[k] = ok ? pos[3 * i + 1] : 0.f;
                zs[k] = ok ? pos[3 * i + 2] : 0.f;
            }
        }
        pair_body(xs[0], ys[0], zs[0], xs[1], ys[1], zs[1], accr, acci);
        pair_body(xs[2], ys[2], zs[2], xs[3], ys[3], zs[3], accr, acci);
    }

    // ---- reduction: wave shuffle -> LDS across 4 waves -> per-block row ----
    __shared__ float red[81][5];   // [out slot][wave], padded stride
    const int lane = threadIdx.x & 63;
    const int wave = threadIdx.x >> 6;

#pragma unroll
    for (int m = 0; m <= NL; ++m) {
#pragma unroll
        for (int l = m; l <= NL; ++l) {
            const int ai = l * (l + 1) / 2 + m;
            float vr = waveReduce(accr[ai]);
            if (lane == 0) red[l * l + l + m][wave] = vr;
            if (m > 0) {
                float vi = waveReduce(acci[ai]);
                if (lane == 0) red[l * l + l - m][wave] = vi;
            }
        }
    }
    __syncthreads();

    // transposed partials: ws[slot*NBLK + block] -> coalesced finalize reads
    if ((int)threadIdx.x < 81) {
        float s = 0.f;
#pragma unroll
        for (int w = 0; w < 4; ++w) s += red[threadIdx.x][w];
        ws[(size_t)threadIdx.x * NBLK + blockIdx.x] = s;
    }
}

__device__ double dfact(int nn) {
    double r = 1.0;
    for (int i = 2; i <= nn; ++i) r *= (double)i;
    return r;
}

// one block per output slot; 256 threads sum 1024 coalesced partials
__global__ __launch_bounds__(256)
void sht_finalize(const float* __restrict__ ws, float* __restrict__ out) {
    const int j = blockIdx.x;       // 0..80
    const int t = threadIdx.x;
    float s = 0.f;
#pragma unroll
    for (int k = 0; k < NBLK / 256; ++k)
        s += ws[(size_t)j * NBLK + k * 256 + t];
    s = waveReduce(s);

    __shared__ float red[4];
    const int lane = t & 63, wave = t >> 6;
    if (lane == 0) red[wave] = s;
    __syncthreads();
    if (t == 0) {
        float tot = red[0] + red[1] + red[2] + red[3];
        int l = 0;
        while ((l + 1) * (l + 1) <= j) ++l;
        const int M = j - l * l - l;
        const int m = (M < 0) ? -M : M;
        // f = sqrt((l+m)!(l-m)!); k_l = sqrt((2l+1)/(4*3.14159))  (ref PI=3.14159)
        double sc = sqrt(dfact(l + m) * dfact(l - m)) *
                    sqrt((double)(2 * l + 1) / (4.0 * 3.14159));
        if (m > 0) sc *= sqrt(2.0) * ((m & 1) ? -1.0 : 1.0);
        out[j] = (float)((double)tot * sc);
    }
}

extern "C" void kernel_launch(void* const* d_in, const int* in_sizes, int n_in,
                              void* d_out, int out_size, void* d_ws, size_t ws_size,
                              hipStream_t stream) {
    const float* pos = (const float*)d_in[0];
    const int npts = in_sizes[0] / 3;
    float* ws = (float*)d_ws;
    float* out = (float*)d_out;

    sht_main<<<NBLK, NTHR, 0, stream>>>(pos, ws, npts);
    sht_finalize<<<81, 256, 0, stream>>>(ws, out);
}

// Round 9
// 138.490 us; speedup vs baseline: 1.3222x; 1.3222x over previous
//
#include <hip/hip_runtime.h>
#include <math.h>

// Problem: SphericalHarmonicTransform, L=8, RCUT=5, N=4194304 points.
// out[81] = sum over points of (modified) solid harmonic terms.
// R9: revert to R7 structure (best, 77us) + two trims:
//     (a) m=0 column scalarized — R7's packed (re,im) pairs carried a dead
//         imag half through 25 sum-terms + 5 Y + 9 acc updates for m=0.
//     (b) 8-point chunks (6x float4) — halves loop/address overhead.
// Model (R1-R8): wall time tracks static instruction count at ~3 wave-instr/
//     cyc/CU; occupancy (2 vs 4 waves/SIMD) and prefetch change nothing;
//     packed fp32 has NO rate advantage on CDNA4 (157.3 TF = scalar rate) and
//     R8's pack/extract-heavy shape regressed to 26% busy. Instruction count
//     is the only working lever.
// Known-bad: launch_bounds(256,4) -> VGPR 64 clamp -> 1.1GB spill (R2);
//     fused finalize w/ fences -> +150us tail (R5); per-point prefetch (R4).

typedef float f32x2 __attribute__((ext_vector_type(2)));

#define NL 8               // L
#define NACC 45            // (l,m) pairs, m<=l, l<=8
#define NBLK 1024
#define NTHR 256

__device__ __forceinline__ f32x2 sp(float v) { return f32x2{v, v}; }

__device__ __forceinline__ f32x2 pkfma(f32x2 a, f32x2 b, f32x2 c) {
    return __builtin_elementwise_fma(a, b, c);
}

__device__ __forceinline__ float waveReduce(float v) {
    v += __shfl_down(v, 32);
    v += __shfl_down(v, 16);
    v += __shfl_down(v, 8);
    v += __shfl_down(v, 4);
    v += __shfl_down(v, 2);
    v += __shfl_down(v, 1);
    return v;
}

// One point, fully unrolled. acc0 = m=0 reals (9); accp = m>=1 (re,im) pairs (36).
__device__ __forceinline__ void point_body(float x, float y, float z,
                                           float* __restrict__ acc0,
                                           f32x2* __restrict__ accp) {
    const float FACT[9] = {1.f, 1.f, 2.f, 6.f, 24.f, 120.f, 720.f, 5040.f, 40320.f};

    const float r2 = x * x + y * y + z * z;
    const bool valid = r2 > 0.0f;
    const float inv0 = __builtin_amdgcn_rsqf(r2);      // 1/sqrt(r2)
    const float norm = r2 * inv0;                      // sqrt(r2); NaN at 0, masked
    float cut = 0.5f * (__cosf(norm * 0.6283185307179586f) + 1.0f);
    cut = (r2 > 25.0f) ? 0.0f : cut;
    cut = valid ? cut : 0.0f;                          // kills NaN at r2=0
    const float inv = valid ? inv0 : 1.0f;             // safe 1/norm
    const float x0c = z * cut;

    // packed chains: lane0 = z1 (xp), lane1 = z2 (xm)
    const f32x2 w  = { -0.5f * x,  0.5f * x };         // (xpr, xmr)
    const f32x2 wi = { -0.5f * y, -0.5f * y };         // (xpi, xmi)

    // powcmplx replication:
    //  n=0 -> (1,0); n=1 -> w; n=2 -> special (r^2-i^2, 2ri);
    //  n>=3 -> buggy chain: nr = wr*br - wi*bi; ni = wr*bi + wi*nr (uses NEW nr)
    //  chain's k=2 real == special real; its (buggy) imag feeds k>=3.
    f32x2 zr[9], zi[9];
    zr[0] = sp(1.f); zi[0] = sp(0.f);
    zr[1] = w;       zi[1] = wi;
    zr[2] = w * w - wi * wi;
    zi[2] = (w + w) * wi;                              // 2*wr*wi
    {
        f32x2 cr = zr[2];
        f32x2 ci = w * wi + wi * cr;                   // buggy chain imag at k=2
#pragma unroll
        for (int k = 3; k <= NL; ++k) {
            const f32x2 nr = w * cr - wi * ci;
            const f32x2 ni = w * ci + wi * nr;         // buggy: uses nr
            cr = nr; ci = ni;
            zr[k] = nr; zi[k] = ni;
        }
    }

    // unpack views
    float aa[9], bb[9], cc[9], dd[9], sqa[9];
#pragma unroll
    for (int p = 0; p <= NL; ++p) {
        aa[p] = zr[p].x;   // z1r
        cc[p] = zr[p].y;   // z2r
        bb[p] = zi[p].x;   // z1i
        dd[p] = zi[p].y;   // z2i
        sqa[p] = aa[p] * aa[p];
    }

    // h_l = x0c * inv^l  (cutoff + 1/r^l deferred out of the sums)
    float h[9];
    h[0] = x0c;
#pragma unroll
    for (int l = 1; l <= NL; ++l) h[l] = h[l - 1] * inv;

    // ---- m = 0: pure-real scalar path (no dead imag work) ----
    {
        float Y0[5];                                    // p = q, p <= 4
#pragma unroll
        for (int p = 0; p <= 4; ++p) {
            const float cpq = 1.0f / (FACT[p] * FACT[p]);       // compile-time
            Y0[p] = fmaf(-dd[p], dd[p], sqa[p]) * cpq;
        }
#pragma unroll
        for (int l = 0; l <= NL; ++l) {
            float sr = 0.f;
#pragma unroll
            for (int p = 0; p <= 4; ++p) {
                if (2 * p <= l) {
                    const float is = 1.0f / FACT[l - 2 * p];    // 9 uniques
                    sr = fmaf(Y0[p], is, sr);
                }
            }
            acc0[l] = fmaf(sr, h[l], acc0[l]);
        }
    }

    // ---- m >= 1: packed (real, imag) ----
#pragma unroll
    for (int m = 1; m <= NL; ++m) {
        f32x2 Y[9];
#pragma unroll
        for (int p = 0; p <= NL; ++p) {
            if (p >= m && 2 * p - m <= NL) {
                const int q = p - m;
                const float cpq = 1.0f / (FACT[p] * FACT[q]);   // compile-time
                const float bc = bb[p] * cc[q];
                const f32x2 A = { -dd[q], aa[p] };
                const f32x2 B = {  dd[q], dd[q] };
                const f32x2 C = { sqa[p], bc };
                Y[p] = pkfma(A, B, C) * sp(cpq);
            }
        }
#pragma unroll
        for (int l = m; l <= NL; ++l) {
            f32x2 s = sp(0.f);
#pragma unroll
            for (int p = 0; p <= NL; ++p) {
                if (p >= m && 2 * p - m <= l) {
                    const float is = 1.0f / FACT[l - 2 * p + m]; // 9 uniques
                    s = pkfma(Y[p], sp(is), s);
                }
            }
            // accp index: pairs (l,m) m>=1 -> l*(l+1)/2 + m - (l+1) offsets; use
            // triangular index over m>=1 only: t(l,m) = l*(l-1)/2 + (m-1)
            const int ai = l * (l - 1) / 2 + (m - 1);
            accp[ai] = pkfma(s, sp(h[l]), accp[ai]);
        }
    }
}

__global__ __launch_bounds__(256, 2)
void sht_main(const float* __restrict__ pos, float* __restrict__ ws, int n) {
    float acc0[9];
    f32x2 accp[36];
#pragma unroll
    for (int i = 0; i < 9; ++i) acc0[i] = 0.f;
#pragma unroll
    for (int i = 0; i < 36; ++i) accp[i] = sp(0.f);

    const int t = blockIdx.x * NTHR + threadIdx.x;
    const int nthreads = NBLK * NTHR;                       // 262144
    const int nchunks = (n / 8 + nthreads - 1) / nthreads;  // 2 for N=2^22

    for (int c = 0; c < nchunks; ++c) {
        const int idx = (c * nthreads + t) * 8;             // 8 contiguous points
        float xs[8], ys[8], zs[8];
        if (idx + 8 <= n) {
            // 6x float4 = 96B, 16B-aligned (idx%8==0 -> offset multiple of 96B)
            const float4* p4 = reinterpret_cast<const float4*>(pos + (size_t)3 * idx);
            const float4 q0 = p4[0], q1 = p4[1], q2 = p4[2];
            const float4 q3 = p4[3], q4 = p4[4], q5 = p4[5];
            xs[0] = q0.x; ys[0] = q0.y; zs[0] = q0.z;
            xs[1] = q0.w; ys[1] = q1.x; zs[1] = q1.y;
            xs[2] = q1.z; ys[2] = q1.w; zs[2] = q2.x;
            xs[3] = q2.y; ys[3] = q2.z; zs[3] = q2.w;
            xs[4] = q3.x; ys[4] = q3.y; zs[4] = q3.z;
            xs[5] = q3.w; ys[5] = q4.x; zs[5] = q4.y;
            xs[6] = q4.z; ys[6] = q4.w; zs[6] = q5.x;
            xs[7] = q5.y; ys[7] = q5.z; zs[7] = q5.w;
        } else {
#pragma unroll
            for (int k = 0; k < 8; ++k) {
                const int i = idx + k;
                const bool ok = i < n;
                xs[k] = ok ? pos[3 * i + 0] : 0.f;          // zero-pad: contributes 0
                ys[k] = ok ? pos[3 * i + 1] : 0.f;
                zs[k] = ok ? pos[3 * i + 2] : 0.f;
            }
        }
#pragma unroll
        for (int k = 0; k < 8; ++k)
            point_body(xs[k], ys[k], zs[k], acc0, accp);
    }

    // ---- reduction: wave shuffle -> LDS across 4 waves -> per-block row ----
    __shared__ float red[81][5];   // [out slot][wave], padded stride
    const int lane = threadIdx.x & 63;
    const int wave = threadIdx.x >> 6;

#pragma unroll
    for (int l = 0; l <= NL; ++l) {
        float vr = waveReduce(acc0[l]);
        if (lane == 0) red[l * l + l][wave] = vr;
    }
#pragma unroll
    for (int m = 1; m <= NL; ++m) {
#pragma unroll
        for (int l = m; l <= NL; ++l) {
            const int ai = l * (l - 1) / 2 + (m - 1);
            float vr = waveReduce(accp[ai].x);
            if (lane == 0) red[l * l + l + m][wave] = vr;
            float vi = waveReduce(accp[ai].y);
            if (lane == 0) red[l * l + l - m][wave] = vi;
        }
    }
    __syncthreads();

    // transposed partials: ws[slot*NBLK + block] -> coalesced finalize reads
    if ((int)threadIdx.x < 81) {
        float s = 0.f;
#pragma unroll
        for (int w = 0; w < 4; ++w) s += red[threadIdx.x][w];
        ws[(size_t)threadIdx.x * NBLK + blockIdx.x] = s;
    }
}

__device__ double dfact(int nn) {
    double r = 1.0;
    for (int i = 2; i <= nn; ++i) r *= (double)i;
    return r;
}

// one block per output slot; 256 threads sum 1024 coalesced partials
__global__ __launch_bounds__(256)
void sht_finalize(const float* __restrict__ ws, float* __restrict__ out) {
    const int j = blockIdx.x;       // 0..80
    const int t = threadIdx.x;
    float s = 0.f;
#pragma unroll
    for (int k = 0; k < NBLK / 256; ++k)
        s += ws[(size_t)j * NBLK + k * 256 + t];
    s = waveReduce(s);

    __shared__ float red[4];
    const int lane = t & 63, wave = t >> 6;
    if (lane == 0) red[wave] = s;
    __syncthreads();
    if (t == 0) {
        float tot = red[0] + red[1] + red[2] + red[3];
        int l = 0;
        while ((l + 1) * (l + 1) <= j) ++l;
        const int M = j - l * l - l;
        const int m = (M < 0) ? -M : M;
        // f = sqrt((l+m)!(l-m)!); k_l = sqrt((2l+1)/(4*3.14159))  (ref PI=3.14159)
        double sc = sqrt(dfact(l + m) * dfact(l - m)) *
                    sqrt((double)(2 * l + 1) / (4.0 * 3.14159));
        if (m > 0) sc *= sqrt(2.0) * ((m & 1) ? -1.0 : 1.0);
        out[j] = (float)((double)tot * sc);
    }
}

extern "C" void kernel_launch(void* const* d_in, const int* in_sizes, int n_in,
                              void* d_out, int out_size, void* d_ws, size_t ws_size,
                              hipStream_t stream) {
    const float* pos = (const float*)d_in[0];
    const int npts = in_sizes[0] / 3;
    float* ws = (float*)d_ws;
    float* out = (float*)d_out;

    sht_main<<<NBLK, NTHR, 0, stream>>>(pos, ws, npts);
    sht_finalize<<<81, 256, 0, stream>>>(ws, out);
}